// Round 4
// baseline (1422.659 us; speedup 1.0000x reference)
//
#include <hip/hip_runtime.h>

#define NN   1000
#define EE   16000
#define FF   64
#define SS   192
#define TNF  768000
#define NB   16
#define NC   10
#define LWG  256   // k_lin_chunk / partials width

typedef unsigned short u16;
typedef unsigned int   u32;
typedef float f32x4_t __attribute__((ext_vector_type(4)));
typedef short s16x4_t __attribute__((ext_vector_type(4)));
typedef short s16x8_t __attribute__((ext_vector_type(8)));

__device__ __forceinline__ float bf2f(u16 u) {
    return __uint_as_float(((u32)u) << 16);
}
__device__ __forceinline__ u16 f2bf(float f) {
    u32 u = __float_as_uint(f);
    u32 r = u + 0x7FFFu + ((u >> 16) & 1u);
    return (u16)(r >> 16);
}
// flag-dispatched scalar float load (f32m: 1 = fp32 array, 0 = bf16 array)
__device__ __forceinline__ float ldf(const void* p, size_t i, int f32m) {
    return f32m ? ((const float*)p)[i] : bf2f(((const u16*)p)[i]);
}

// ---------------- dtype detection ----------------
// flags[0]: 1 if float arrays are fp32, 0 if bf16.  flags[1]: 1 if edge_index is int64.
__global__ void k_detect(const u16* __restrict__ x, const int* __restrict__ ei,
                         int* __restrict__ flags) {
    if (threadIdx.x == 0) {
        int good = 0;
        for (int i = 0; i < 256; i += 2) {       // even words: bf16 values if bf16 array
            u16 u = x[i];
            int e = (u >> 7) & 0xFF;
            if (u == 0 || (e >= 100 && e <= 140)) ++good;
        }
        flags[0] = (good < 96) ? 1 : 0;          // <75% plausible -> fp32
        int nz = 0;
        for (int i = 1; i < 64; i += 2) nz += (ei[i] != 0);
        flags[1] = (nz <= 4) ? 1 : 0;            // odd words all zero -> int64
    }
}

// ---------------- prep kernels ----------------

__global__ void k_zero(int* __restrict__ p) {
    int i = blockIdx.x * 256 + threadIdx.x;
    if (i < 4000) p[i] = 0;
}

__global__ void k_zpart(float* __restrict__ p) {
    int i = blockIdx.x * 256 + threadIdx.x;
    if (i < LWG * 160) p[i] = 0.f;
}

// deg block: [0..999]=deg_out, [1000..1999]=deg_in, [2000..3999]=cursors
__global__ void k_deg(const int* __restrict__ ei, int* __restrict__ deg,
                      const int* __restrict__ flags) {
    int e = blockIdx.x * 256 + threadIdx.x;
    const int sh = flags[1];
    if (e < EE) {
        int r = ei[(size_t)e << sh];
        int c = ei[(size_t)(EE + e) << sh];
        atomicAdd(&deg[r & 1023], 1);             // out-degree of src
        atomicAdd(&deg[NN + (c & 1023)], 1);      // in-degree of dst
    }
}

__global__ __launch_bounds__(1024) void k_scan(const int* __restrict__ deg_in,
        const int* __restrict__ deg_out, int* __restrict__ ooff, int* __restrict__ ioff,
        float* __restrict__ inv_o, float* __restrict__ inv_i) {
    __shared__ int sa[1024], sb2[1024];
    const int t = threadIdx.x;
    for (int pass = 0; pass < 2; ++pass) {
        const int* deg = pass ? deg_out : deg_in;
        int* dst_off = pass ? ioff : ooff;
        sa[t] = (t < NN) ? deg[t] : 0;
        __syncthreads();
        int* src = sa; int* dst = sb2;
        for (int offn = 1; offn < 1024; offn <<= 1) {
            int v = src[t];
            if (t >= offn) v += src[t - offn];
            dst[t] = v;
            __syncthreads();
            int* tmp = src; src = dst; dst = tmp;
        }
        if (t == 0) dst_off[0] = 0;
        if (t < NN) dst_off[t + 1] = src[t];
        __syncthreads();
    }
    if (t < NN) {
        inv_o[t] = 1.0f / (float)max(deg_out[t], 1);
        inv_i[t] = 1.0f / (float)max(deg_in[t], 1);
    }
}

__global__ void k_fill(const int* __restrict__ ei, const int* __restrict__ ooff,
        const int* __restrict__ ioff, const float* __restrict__ inv_o,
        int* __restrict__ cur, int2* __restrict__ eo, int* __restrict__ eid,
        const int* __restrict__ flags) {
    int e = blockIdx.x * 256 + threadIdx.x;
    const int sh = flags[1];
    if (e < EE) {
        int r = ei[(size_t)e << sh] & 1023;
        int c = ei[(size_t)(EE + e) << sh] & 1023;
        int po = ooff[c] + atomicAdd(&cur[c], 1);       // group by dst
        eo[po] = make_int2(r, __float_as_int(inv_o[r]));
        int pi = ioff[r] + atomicAdd(&cur[NN + r], 1);  // group by src
        eid[pi] = c;
    }
}

// Wt[col][kappa], kappa = j*64 + fi.  col<64 -> z (W_z), col>=64 -> h (W_h).
__global__ void k_wt(const void* __restrict__ Wz, const void* __restrict__ Wh,
                     u16* __restrict__ wt, const int* __restrict__ flags) {
    int idx = blockIdx.x * 256 + threadIdx.x;
    if (idx >= 128 * 576) return;
    const int f32m = flags[0];
    const int col = idx / 576;
    const int kk = idx - col * 576;
    const int j = kk >> 6, fi = kk & 63;
    const void* W = (col < 64) ? Wz : Wh;
    const int fo = col & 63;
    float v;
    if (j == 0) {
        v = ldf(W, (size_t)(0 * 128 + fi) * 64 + fo, f32m)
          + ldf(W, (size_t)(5 * 128 + fi) * 64 + fo, f32m);
    } else {
        const int d = (j & 1) ? 0 : 1;
        const int kq = (j + 1) >> 1;
        v = ldf(W, (size_t)((d * 5 + kq) * 128 + fi) * 64 + fo, f32m);
    }
    wt[col * 576 + kk] = f2bf(v);
}

// ---------------- phase 1: Chebyshev basis ----------------
// basis: [sb(16)][j(9)][row(rchp)][f4(4)] bf16

__device__ __forceinline__ void stb(u16* __restrict__ basis, int sb, int j, int row,
                                    int rchp, float4 v) {
    ushort4 u = make_ushort4(f2bf(v.x), f2bf(v.y), f2bf(v.z), f2bf(v.w));
    *(ushort4*)(basis + ((size_t)(sb * 9 + j) * rchp + row) * 4) = u;
}

__device__ __forceinline__ float4 gO(const float4* __restrict__ S, const int2* __restrict__ eo,
                                     int e0, int e1) {
    float4 a = make_float4(0.f, 0.f, 0.f, 0.f);
    for (int e = e0; e < e1; ++e) {
        int2 p = eo[e];
        float w = __int_as_float(p.y);
        float4 v = S[p.x];
        a.x = fmaf(w, v.x, a.x); a.y = fmaf(w, v.y, a.y);
        a.z = fmaf(w, v.z, a.z); a.w = fmaf(w, v.w, a.w);
    }
    return a;
}
__device__ __forceinline__ float4 gI(const float4* __restrict__ S, const int* __restrict__ eid,
                                     int e0, int e1) {
    float4 a = make_float4(0.f, 0.f, 0.f, 0.f);
    for (int e = e0; e < e1; ++e) {
        float4 v = S[eid[e]];
        a.x += v.x; a.y += v.y; a.z += v.z; a.w += v.w;
    }
    return a;
}

__global__ __launch_bounds__(1024) void k_cheb(const void* __restrict__ xv_,
        const int2* __restrict__ eo, const int* __restrict__ ooff,
        const int* __restrict__ eid, const int* __restrict__ ioff,
        const float* __restrict__ inv_i, u16* __restrict__ basis, int s0, int rchp,
        const int* __restrict__ flags) {
    __shared__ float4 bX[NN], bA[NN], bB[NN], bC[NN];
    const int slocal = blockIdx.x >> 4;
    const int sb = blockIdx.x & 15;       // feature slice of 4
    const int s = s0 + slocal;
    const int n = threadIdx.x;
    const bool act = (n < NN);
    const int f32m = flags[0];
    int e0o = 0, e1o = 0, e0i = 0, e1i = 0;
    float fiv = 0.f;
    const int row = slocal * NN + n;
    if (act) {
        e0o = ooff[n]; e1o = ooff[n + 1];
        e0i = ioff[n]; e1i = ioff[n + 1];
        fiv = inv_i[n];
    }
    const float fiv2 = 2.f * fiv;
    if (act) {
        const size_t xoff = ((size_t)s * NN + n) * FF + sb * 4;
        float4 xv;
        if (f32m) {
            xv = *(const float4*)((const float*)xv_ + xoff);
        } else {
            ushort4 u = *(const ushort4*)((const u16*)xv_ + xoff);
            xv = make_float4(bf2f(u.x), bf2f(u.y), bf2f(u.z), bf2f(u.w));
        }
        bX[n] = xv;
        stb(basis, sb, 0, row, rchp, xv);       // j0 = Tx0 = x
    }
    __syncthreads();
    // 1: A = Po(X)                                -> j1 = T1o
    if (act) { float4 g = gO(bX, eo, e0o, e1o); bA[n] = g; stb(basis, sb, 1, row, rchp, g); }
    __syncthreads();
    // 2: B = fiv*Pi(X)                            -> j2 = T1i
    if (act) {
        float4 g = gI(bX, eid, e0i, e1i);
        float4 t = make_float4(g.x * fiv, g.y * fiv, g.z * fiv, g.w * fiv);
        bB[n] = t; stb(basis, sb, 2, row, rchp, t);
    }
    __syncthreads();
    // 3: C = 2*Po(A) - X                          -> j3 = T2o
    if (act) {
        float4 g = gO(bA, eo, e0o, e1o); float4 sv = bX[n];
        float4 t = make_float4(fmaf(2.f, g.x, -sv.x), fmaf(2.f, g.y, -sv.y),
                               fmaf(2.f, g.z, -sv.z), fmaf(2.f, g.w, -sv.w));
        bC[n] = t; stb(basis, sb, 3, row, rchp, t);
    }
    __syncthreads();
    // 4: X = 2*fiv*Pi(B) - X                      -> j4 = T2i
    if (act) {
        float4 g = gI(bB, eid, e0i, e1i); float4 sv = bX[n];
        float4 t = make_float4(fmaf(fiv2, g.x, -sv.x), fmaf(fiv2, g.y, -sv.y),
                               fmaf(fiv2, g.z, -sv.z), fmaf(fiv2, g.w, -sv.w));
        bX[n] = t; stb(basis, sb, 4, row, rchp, t);
    }
    __syncthreads();
    // 5: B = 2*Po(C) - A  (A still T1o)           -> j5 = T3o
    if (act) {
        float4 g = gO(bC, eo, e0o, e1o); float4 sv = bA[n];
        float4 t = make_float4(fmaf(2.f, g.x, -sv.x), fmaf(2.f, g.y, -sv.y),
                               fmaf(2.f, g.z, -sv.z), fmaf(2.f, g.w, -sv.w));
        bB[n] = t; stb(basis, sb, 5, row, rchp, t);
    }
    __syncthreads();
    // 6: A = 2*fiv*Pi(X) - A  (subtrahend T1o — reference's shared-buffer quirk) -> j6 = T3i
    if (act) {
        float4 g = gI(bX, eid, e0i, e1i); float4 sv = bA[n];
        float4 t = make_float4(fmaf(fiv2, g.x, -sv.x), fmaf(fiv2, g.y, -sv.y),
                               fmaf(fiv2, g.z, -sv.z), fmaf(fiv2, g.w, -sv.w));
        bA[n] = t; stb(basis, sb, 6, row, rchp, t);
    }
    __syncthreads();
    // 7: X = 2*Po(B) - C                          -> j7 = T4o
    if (act) {
        float4 g = gO(bB, eo, e0o, e1o); float4 sv = bC[n];
        float4 t = make_float4(fmaf(2.f, g.x, -sv.x), fmaf(2.f, g.y, -sv.y),
                               fmaf(2.f, g.z, -sv.z), fmaf(2.f, g.w, -sv.w));
        bX[n] = t; stb(basis, sb, 7, row, rchp, t);
    }
    __syncthreads();
    // 8: C = 2*fiv*Pi(A) - C  (subtrahend T2o)    -> j8 = T4i
    if (act) {
        float4 g = gI(bA, eid, e0i, e1i); float4 sv = bC[n];
        float4 t = make_float4(fmaf(fiv2, g.x, -sv.x), fmaf(fiv2, g.y, -sv.y),
                               fmaf(fiv2, g.z, -sv.z), fmaf(fiv2, g.w, -sv.w));
        bC[n] = t; stb(basis, sb, 8, row, rchp, t);
    }
}

// ---------------- phase 2: GEMM [rchp,576]@[576,128] + gates + LN -> hnc (chunk-local) ----------------

__global__ __launch_bounds__(256, 4) void k_gemm(const u16* __restrict__ basis,
        const u16* __restrict__ wt, const void* __restrict__ bz, const void* __restrict__ bh,
        const void* __restrict__ lng, const void* __restrict__ lnb, u16* __restrict__ hnc,
        int rchp, int rchv, const int* __restrict__ flags) {
    union SM {
        struct { u16 A[8 * 128 * 4]; u16 B[128 * 40]; } st;
        float heh[128 * 65];
    };
    __shared__ SM sm;
    __shared__ float sMu[128], sRs[128];
    __shared__ float sBz[64], sBh[64], sG[64], sB2[64];

    const int tid = threadIdx.x;
    if (tid < 64) {
        const int f32m = flags[0];
        sBz[tid] = ldf(bz, tid, f32m); sBh[tid] = ldf(bh, tid, f32m);
        sG[tid] = ldf(lng, tid, f32m); sB2[tid] = ldf(lnb, tid, f32m);
    }
    const int lane = tid & 63, wv = tid >> 6;
    const int wr = wv >> 1, wc = wv & 1;
    const int m = lane & 15, q = lane >> 4;
    const int r0 = blockIdx.x * 128;

    f32x4_t acc[4][4];
    const f32x4_t zero = {0.f, 0.f, 0.f, 0.f};
    for (int mi = 0; mi < 4; ++mi)
        for (int ni = 0; ni < 4; ++ni) acc[mi][ni] = zero;

    for (int t = 0; t < 18; ++t) {
        const int j = t >> 1, hf = t & 1;
        #pragma unroll
        for (int p = 0; p < 2; ++p) {
            int lin = p * 256 + tid;
            int sbp = lin >> 6, rp = lin & 63;
            const u16* src = basis + ((size_t)((hf * 8 + sbp) * 9 + j) * rchp + r0 + rp * 2) * 4;
            *(uint4*)(&sm.st.A[lin * 8]) = *(const uint4*)src;
        }
        #pragma unroll
        for (int p = 0; p < 2; ++p) {
            int lin = p * 256 + tid;
            int c = lin >> 2, qq = lin & 3;
            const u16* src = wt + c * 576 + t * 32 + qq * 8;
            *(uint4*)(&sm.st.B[c * 40 + qq * 8]) = *(const uint4*)src;
        }
        __syncthreads();
        s16x8_t af[4], bfr[4];
        #pragma unroll
        for (int mi = 0; mi < 4; ++mi) {
            int r = wr * 64 + mi * 16 + m;
            s16x4_t lo = *(const s16x4_t*)&sm.st.A[(2 * q) * 512 + r * 4];
            s16x4_t hi = *(const s16x4_t*)&sm.st.A[(2 * q + 1) * 512 + r * 4];
            af[mi] = __builtin_shufflevector(lo, hi, 0, 1, 2, 3, 4, 5, 6, 7);
        }
        #pragma unroll
        for (int ni = 0; ni < 4; ++ni) {
            int c = (ni < 2) ? (wc * 32 + ni * 16 + m) : (64 + wc * 32 + (ni - 2) * 16 + m);
            bfr[ni] = *(const s16x8_t*)&sm.st.B[c * 40 + q * 8];
        }
        #pragma unroll
        for (int mi = 0; mi < 4; ++mi)
            #pragma unroll
            for (int ni = 0; ni < 4; ++ni)
                acc[mi][ni] = __builtin_amdgcn_mfma_f32_16x16x32_bf16(af[mi], bfr[ni], acc[mi][ni], 0, 0, 0);
        __syncthreads();
    }

    #pragma unroll
    for (int mi = 0; mi < 4; ++mi) {
        #pragma unroll
        for (int ni = 0; ni < 2; ++ni) {
            const int f = wc * 32 + ni * 16 + m;
            const float vbz = sBz[f], vbh = sBh[f];
            #pragma unroll
            for (int r = 0; r < 4; ++r) {
                const int rl = wr * 64 + mi * 16 + q * 4 + r;
                float zp = acc[mi][ni][r];
                float hp = acc[mi][ni + 2][r];
                zp = (zp == zp) ? zp : 0.f;   // NaN scrub (diagnostic guarantee: finite output)
                hp = (hp == hp) ? hp : 0.f;
                zp = fminf(fmaxf(zp + vbz, -30.f), 30.f);
                hp = fminf(fmaxf(hp + vbh, -15.f), 15.f);
                const float z = __fdividef(1.f, 1.f + __expf(-zp));
                const float e2 = __expf(2.f * hp);
                const float ht = __fdividef(e2 - 1.f, e2 + 1.f);
                float h = (1.f - z) * ht;
                h = fmaxf(h, 0.f);
                sm.heh[rl * 65 + f] = h;
            }
        }
    }
    __syncthreads();
    if (tid < 128) {
        float sum = 0.f, ss = 0.f;
        #pragma unroll 8
        for (int f = 0; f < 64; ++f) {
            float v = sm.heh[tid * 65 + f];
            sum += v; ss += v * v;
        }
        float mu = sum * 0.015625f;
        float var = fmaxf(ss * 0.015625f - mu * mu, 0.f);
        sMu[tid] = mu;
        sRs[tid] = rsqrtf(var + 1e-5f);
    }
    __syncthreads();
    for (int idx = tid; idx < 128 * 64; idx += 256) {
        int rl = idx >> 6, f = idx & 63;
        if (r0 + rl < rchv) {
            float v = (sm.heh[rl * 65 + f] - sMu[rl]) * sRs[rl] * sG[f] + sB2[f];
            hnc[(size_t)(r0 + rl) * 64 + f] = f2bf(v);
        }
    }
}

// ---------------- phase 3: chunked final linear (accumulates into partials) ----------------
// chunk covers snapshots s in [s0, s0+chs). s = b*12 + t. within-batch flat idx = t*64000 + i2.

__global__ __launch_bounds__(256) void k_lin_chunk(const u16* __restrict__ hnc,
        const void* __restrict__ lw, float* __restrict__ partials, int s0, int chs,
        const int* __restrict__ flags) {
    const int tid = threadIdx.x;
    const int f32m = flags[0];
    float acc[NB][NC];
    #pragma unroll
    for (int b = 0; b < NB; ++b)
        #pragma unroll
        for (int c = 0; c < NC; ++c) acc[b][c] = 0.f;

    const int hi_s = s0 + chs - 1;
    for (int w = blockIdx.x * 256 + tid; w < TNF; w += LWG * 256) {
        const int t = w / 64000;
        int blo_n = s0 - t + 11;
        const int blo = (blo_n > 0) ? (blo_n / 12) : 0;
        const int bhi_n = hi_s - t;
        const int bhi = (bhi_n >= 0) ? (bhi_n / 12) : -1;
        if (bhi < blo) continue;
        float wvv[NC];
        if (f32m) {
            #pragma unroll
            for (int c = 0; c < NC; ++c) wvv[c] = ((const float*)lw)[(size_t)c * TNF + w];
        } else {
            #pragma unroll
            for (int c = 0; c < NC; ++c) wvv[c] = bf2f(((const u16*)lw)[(size_t)c * TNF + w]);
        }
        #pragma unroll
        for (int c = 0; c < NC; ++c) {
            float v = wvv[c];
            wvv[c] = (v == v && v > -1e30f && v < 1e30f) ? v : 0.f;  // scrub
        }
        #pragma unroll
        for (int b = 0; b < NB; ++b) {
            if (b >= blo && b <= bhi) {
                const int sl = b * 12 + t - s0;            // local snapshot row
                const float h = bf2f(hnc[(size_t)sl * 64000 + (w - t * 64000)]);
                #pragma unroll
                for (int c = 0; c < NC; ++c) acc[b][c] = fmaf(h, wvv[c], acc[b][c]);
            }
        }
    }
    __shared__ float sRed[4][160];
    const int wvi = tid >> 6, lane = tid & 63;
    #pragma unroll
    for (int b = 0; b < NB; ++b)
        #pragma unroll
        for (int c = 0; c < NC; ++c) {
            float v = acc[b][c];
            #pragma unroll
            for (int off = 1; off < 64; off <<= 1) v += __shfl_xor(v, off, 64);
            if (lane == 0) sRed[wvi][b * NC + c] = v;
        }
    __syncthreads();
    if (tid < 160)
        partials[(size_t)blockIdx.x * 160 + tid] +=
            sRed[0][tid] + sRed[1][tid] + sRed[2][tid] + sRed[3][tid];
}

__global__ void k_red(const float* __restrict__ partials, const void* __restrict__ lb,
                      void* __restrict__ out, const int* __restrict__ flags) {
    const int o = threadIdx.x;
    const int f32m = flags[0];
    if (o < 160) {
        float s = ldf(lb, o % NC, f32m);
        #pragma unroll 8
        for (int wg = 0; wg < LWG; ++wg) s += partials[(size_t)wg * 160 + o];
        if (f32m) ((float*)out)[o] = s;
        else      ((u16*)out)[o] = f2bf(s);
    }
}

// ---------------- launch ----------------

extern "C" void kernel_launch(void* const* d_in, const int* in_sizes, int n_in,
                              void* d_out, int out_size, void* d_ws, size_t ws_size,
                              hipStream_t stream) {
    (void)in_sizes; (void)n_in; (void)out_size;
    const void* x   = d_in[0];
    const int*  ei  = (const int*)d_in[1];
    const void* Wz  = d_in[2];
    const void* bz  = d_in[3];
    const void* Wh  = d_in[6];
    const void* bh  = d_in[7];
    const void* lng = d_in[8];
    const void* lnb = d_in[9];
    const void* lw  = d_in[10];
    const void* lb  = d_in[11];

    char* ws = (char*)d_ws;
    size_t off = 0;
    auto alloc = [&](size_t bytes) -> void* {
        void* p = ws + off;
        off = (off + bytes + 255) & ~(size_t)255;
        return p;
    };
    // fixed small allocations (~0.8 MB)
    int*   flags    = (int*)  alloc(64);
    u16*   wt       = (u16*)  alloc(128 * 576 * 2);
    int*   ints     = (int*)  alloc(4000 * 4);       // deg_out, deg_in, cursors
    int*   ooff     = (int*)  alloc(1024 * 4);
    int*   ioff     = (int*)  alloc(1024 * 4);
    float* inv_o    = (float*)alloc(1000 * 4);
    float* inv_i    = (float*)alloc(1000 * 4);
    int2*  eo       = (int2*) alloc((size_t)EE * 8);
    int*   eid      = (int*)  alloc((size_t)EE * 4);
    float* partials = (float*)alloc((size_t)LWG * 160 * 4);

    // pick the largest chunk size (divisor of 192) fitting basis + chunk-local hnc
    const int cand[] = {192, 96, 64, 48, 32, 24, 16, 12, 8, 6, 4, 3, 2, 1};
    int CHS = 1, RCHP = 1024;
    for (int ci = 0; ci < 14; ++ci) {
        int c = cand[ci];
        int rchp = ((c * NN + 127) / 128) * 128;
        size_t need = (size_t)16 * 9 * rchp * 8 + (size_t)c * NN * FF * 2 + 8192;
        if (off + need <= ws_size) { CHS = c; RCHP = rchp; break; }
    }
    u16* basis = (u16*)alloc((size_t)16 * 9 * RCHP * 8);
    u16* hnc   = (u16*)alloc((size_t)CHS * NN * FF * 2);

    int* deg_out = ints;
    int* deg_in  = ints + 1000;
    int* cur     = ints + 2000;

    k_detect<<<1, 64, 0, stream>>>((const u16*)x, ei, flags);
    k_zero<<<16, 256, 0, stream>>>(ints);
    k_zpart<<<(LWG * 160 + 255) / 256, 256, 0, stream>>>(partials);
    k_deg<<<(EE + 255) / 256, 256, 0, stream>>>(ei, ints, flags);
    k_scan<<<1, 1024, 0, stream>>>(deg_in, deg_out, ooff, ioff, inv_o, inv_i);
    k_fill<<<(EE + 255) / 256, 256, 0, stream>>>(ei, ooff, ioff, inv_o, cur, eo, eid, flags);
    k_wt<<<288, 256, 0, stream>>>(Wz, Wh, wt, flags);
    const int nchunk = SS / CHS;
    for (int ch = 0; ch < nchunk; ++ch) {
        k_cheb<<<CHS * 16, 1024, 0, stream>>>(x, eo, ooff, eid, ioff, inv_i, basis,
                                              ch * CHS, RCHP, flags);
        k_gemm<<<RCHP / 128, 256, 0, stream>>>(basis, wt, bz, bh, lng, lnb, hnc,
                                               RCHP, CHS * NN, flags);
        k_lin_chunk<<<LWG, 256, 0, stream>>>(hnc, lw, partials, ch * CHS, CHS, flags);
    }
    k_red<<<1, 256, 0, stream>>>(partials, lb, d_out, flags);
}

// Round 5
// 746.635 us; speedup vs baseline: 1.9054x; 1.9054x over previous
//
#include <hip/hip_runtime.h>

#define NN   1000
#define EE   16000
#define FF   64
#define SS   192
#define TNF  768000
#define NB   16
#define NC   10
#define LWG  256   // k_lin_chunk / partials width

typedef unsigned short u16;
typedef unsigned int   u32;
typedef float f32x4_t __attribute__((ext_vector_type(4)));
typedef short s16x4_t __attribute__((ext_vector_type(4)));
typedef short s16x8_t __attribute__((ext_vector_type(8)));

__device__ __forceinline__ float bf2f(u16 u) {
    return __uint_as_float(((u32)u) << 16);
}
__device__ __forceinline__ u16 f2bf(float f) {
    u32 u = __float_as_uint(f);
    u32 r = u + 0x7FFFu + ((u >> 16) & 1u);
    return (u16)(r >> 16);
}
// flag-dispatched scalar float load (f32m: 1 = fp32 array, 0 = bf16 array)
__device__ __forceinline__ float ldf(const void* p, size_t i, int f32m) {
    return f32m ? ((const float*)p)[i] : bf2f(((const u16*)p)[i]);
}

// ---------------- dtype detection ----------------
__global__ void k_detect(const u16* __restrict__ x, const int* __restrict__ ei,
                         int* __restrict__ flags) {
    if (threadIdx.x == 0) {
        int good = 0;
        for (int i = 0; i < 256; i += 2) {
            u16 u = x[i];
            int e = (u >> 7) & 0xFF;
            if (u == 0 || (e >= 100 && e <= 140)) ++good;
        }
        flags[0] = (good < 96) ? 1 : 0;          // <75% plausible -> fp32
        int nz = 0;
        for (int i = 1; i < 64; i += 2) nz += (ei[i] != 0);
        flags[1] = (nz <= 4) ? 1 : 0;            // odd words all zero -> int64
    }
}

// ---------------- prep kernels ----------------

__global__ void k_zero(int* __restrict__ p) {
    int i = blockIdx.x * 256 + threadIdx.x;
    if (i < 4000) p[i] = 0;
}

__global__ void k_zpart(float* __restrict__ p) {
    int i = blockIdx.x * 256 + threadIdx.x;
    if (i < LWG * 160) p[i] = 0.f;
}

__global__ void k_deg(const int* __restrict__ ei, int* __restrict__ deg,
                      const int* __restrict__ flags) {
    int e = blockIdx.x * 256 + threadIdx.x;
    const int sh = flags[1];
    if (e < EE) {
        int r = ei[(size_t)e << sh];
        int c = ei[(size_t)(EE + e) << sh];
        atomicAdd(&deg[r & 1023], 1);
        atomicAdd(&deg[NN + (c & 1023)], 1);
    }
}

__global__ __launch_bounds__(1024) void k_scan(const int* __restrict__ deg_in,
        const int* __restrict__ deg_out, int* __restrict__ ooff, int* __restrict__ ioff,
        float* __restrict__ inv_o, float* __restrict__ inv_i) {
    __shared__ int sa[1024], sb2[1024];
    const int t = threadIdx.x;
    for (int pass = 0; pass < 2; ++pass) {
        const int* deg = pass ? deg_out : deg_in;
        int* dst_off = pass ? ioff : ooff;
        sa[t] = (t < NN) ? deg[t] : 0;
        __syncthreads();
        int* src = sa; int* dst = sb2;
        for (int offn = 1; offn < 1024; offn <<= 1) {
            int v = src[t];
            if (t >= offn) v += src[t - offn];
            dst[t] = v;
            __syncthreads();
            int* tmp = src; src = dst; dst = tmp;
        }
        if (t == 0) dst_off[0] = 0;
        if (t < NN) dst_off[t + 1] = src[t];
        __syncthreads();
    }
    if (t < NN) {
        inv_o[t] = 1.0f / (float)max(deg_out[t], 1);
        inv_i[t] = 1.0f / (float)max(deg_in[t], 1);
    }
}

__global__ void k_fill(const int* __restrict__ ei, const int* __restrict__ ooff,
        const int* __restrict__ ioff, const float* __restrict__ inv_o,
        int* __restrict__ cur, int2* __restrict__ eo, int* __restrict__ eid,
        const int* __restrict__ flags) {
    int e = blockIdx.x * 256 + threadIdx.x;
    const int sh = flags[1];
    if (e < EE) {
        int r = ei[(size_t)e << sh] & 1023;
        int c = ei[(size_t)(EE + e) << sh] & 1023;
        int po = ooff[c] + atomicAdd(&cur[c], 1);       // group by dst
        eo[po] = make_int2(r, __float_as_int(inv_o[r]));
        int pi = ioff[r] + atomicAdd(&cur[NN + r], 1);  // group by src
        eid[pi] = c;
    }
}

// Wt[col][kappa], kappa = j*64 + fi.  col<64 -> z (W_z), col>=64 -> h (W_h).
__global__ void k_wt(const void* __restrict__ Wz, const void* __restrict__ Wh,
                     u16* __restrict__ wt, const int* __restrict__ flags) {
    int idx = blockIdx.x * 256 + threadIdx.x;
    if (idx >= 128 * 576) return;
    const int f32m = flags[0];
    const int col = idx / 576;
    const int kk = idx - col * 576;
    const int j = kk >> 6, fi = kk & 63;
    const void* W = (col < 64) ? Wz : Wh;
    const int fo = col & 63;
    float v;
    if (j == 0) {
        v = ldf(W, (size_t)(0 * 128 + fi) * 64 + fo, f32m)
          + ldf(W, (size_t)(5 * 128 + fi) * 64 + fo, f32m);
    } else {
        const int d = (j & 1) ? 0 : 1;
        const int kq = (j + 1) >> 1;
        v = ldf(W, (size_t)((d * 5 + kq) * 128 + fi) * 64 + fo, f32m);
    }
    wt[col * 576 + kk] = f2bf(v);
}

// ---------------- phase 1: Chebyshev basis ----------------
// basis: [sb(16)][j(9)][row(rchp)][f4(4)] bf16

__device__ __forceinline__ void stb(u16* __restrict__ basis, int sb, int j, int row,
                                    int rchp, float4 v) {
    ushort4 u = make_ushort4(f2bf(v.x), f2bf(v.y), f2bf(v.z), f2bf(v.w));
    *(ushort4*)(basis + ((size_t)(sb * 9 + j) * rchp + row) * 4) = u;
}

// 4-edge-batched gathers: independent loads per iteration -> ~4x ILP on the latency chain
__device__ __forceinline__ float4 gO4(const float4* __restrict__ S, const int2* __restrict__ eo,
                                      int e0, int e1) {
    float4 a = make_float4(0.f, 0.f, 0.f, 0.f);
    int e = e0;
    for (; e + 4 <= e1; e += 4) {
        int2 p0 = eo[e], p1 = eo[e + 1], p2 = eo[e + 2], p3 = eo[e + 3];
        float4 v0 = S[p0.x], v1 = S[p1.x], v2 = S[p2.x], v3 = S[p3.x];
        float w0 = __int_as_float(p0.y), w1 = __int_as_float(p1.y);
        float w2 = __int_as_float(p2.y), w3 = __int_as_float(p3.y);
        a.x = fmaf(w0, v0.x, a.x); a.y = fmaf(w0, v0.y, a.y);
        a.z = fmaf(w0, v0.z, a.z); a.w = fmaf(w0, v0.w, a.w);
        a.x = fmaf(w1, v1.x, a.x); a.y = fmaf(w1, v1.y, a.y);
        a.z = fmaf(w1, v1.z, a.z); a.w = fmaf(w1, v1.w, a.w);
        a.x = fmaf(w2, v2.x, a.x); a.y = fmaf(w2, v2.y, a.y);
        a.z = fmaf(w2, v2.z, a.z); a.w = fmaf(w2, v2.w, a.w);
        a.x = fmaf(w3, v3.x, a.x); a.y = fmaf(w3, v3.y, a.y);
        a.z = fmaf(w3, v3.z, a.z); a.w = fmaf(w3, v3.w, a.w);
    }
    for (; e < e1; ++e) {
        int2 p = eo[e];
        float w = __int_as_float(p.y);
        float4 v = S[p.x];
        a.x = fmaf(w, v.x, a.x); a.y = fmaf(w, v.y, a.y);
        a.z = fmaf(w, v.z, a.z); a.w = fmaf(w, v.w, a.w);
    }
    return a;
}
__device__ __forceinline__ float4 gI4(const float4* __restrict__ S, const int* __restrict__ eid,
                                      int e0, int e1) {
    float4 a = make_float4(0.f, 0.f, 0.f, 0.f);
    int e = e0;
    for (; e + 4 <= e1; e += 4) {
        int i0 = eid[e], i1 = eid[e + 1], i2 = eid[e + 2], i3 = eid[e + 3];
        float4 v0 = S[i0], v1 = S[i1], v2 = S[i2], v3 = S[i3];
        a.x += v0.x + v1.x + v2.x + v3.x;
        a.y += v0.y + v1.y + v2.y + v3.y;
        a.z += v0.z + v1.z + v2.z + v3.z;
        a.w += v0.w + v1.w + v2.w + v3.w;
    }
    for (; e < e1; ++e) {
        float4 v = S[eid[e]];
        a.x += v.x; a.y += v.y; a.z += v.z; a.w += v.w;
    }
    return a;
}

// 4 merged phases (was 9 barrier-separated steps). Hazard audit per phase:
//  ph12: gathers read bX; writes bA(T1o), bB(T1i)
//  ph34: gathers read bA,bB; own-elem read bX; writes bC(T2o), bX(T2i)
//  ph56: gathers read bC,bX; own-elem read bA(T1o quirk); writes bB(T3o), bA(T3i)
//  ph78: gathers read bB,bA; own-elem read bC(T2o quirk); no LDS writes
__global__ __launch_bounds__(1024) void k_cheb(const void* __restrict__ xv_,
        const int2* __restrict__ eo, const int* __restrict__ ooff,
        const int* __restrict__ eid, const int* __restrict__ ioff,
        const float* __restrict__ inv_i, u16* __restrict__ basis, int s0, int rchp,
        const int* __restrict__ flags, int chs) {
    __shared__ float4 bX[NN], bA[NN], bB[NN], bC[NN];
    // swizzle: sb = blockIdx/chs so all 16 slices of a snapshot share an XCD (chs % 8 == 0)
    const int sb = blockIdx.x / chs;
    const int slocal = blockIdx.x - sb * chs;
    const int s = s0 + slocal;
    const int n = threadIdx.x;
    const bool act = (n < NN);
    const int f32m = flags[0];
    int e0o = 0, e1o = 0, e0i = 0, e1i = 0;
    float fiv = 0.f;
    const int row = slocal * NN + n;
    if (act) {
        e0o = ooff[n]; e1o = ooff[n + 1];
        e0i = ioff[n]; e1i = ioff[n + 1];
        fiv = inv_i[n];
    }
    const float fiv2 = 2.f * fiv;
    if (act) {
        const size_t xoff = ((size_t)s * NN + n) * FF + sb * 4;
        float4 xv;
        if (f32m) {
            xv = *(const float4*)((const float*)xv_ + xoff);
        } else {
            ushort4 u = *(const ushort4*)((const u16*)xv_ + xoff);
            xv = make_float4(bf2f(u.x), bf2f(u.y), bf2f(u.z), bf2f(u.w));
        }
        bX[n] = xv;
        stb(basis, sb, 0, row, rchp, xv);       // j0 = Tx0 = x
    }
    __syncthreads();
    // ph12: T1o -> bA (j1), T1i -> bB (j2)
    if (act) {
        float4 go = gO4(bX, eo, e0o, e1o);
        float4 gi = gI4(bX, eid, e0i, e1i);
        bA[n] = go; stb(basis, sb, 1, row, rchp, go);
        float4 t = make_float4(gi.x * fiv, gi.y * fiv, gi.z * fiv, gi.w * fiv);
        bB[n] = t; stb(basis, sb, 2, row, rchp, t);
    }
    __syncthreads();
    // ph34: T2o = 2*gO(bA)-X -> bC (j3); T2i = fiv2*gI(bB)-X -> bX (j4)
    if (act) {
        float4 go = gO4(bA, eo, e0o, e1o);
        float4 gi = gI4(bB, eid, e0i, e1i);
        float4 sv = bX[n];
        float4 t2o = make_float4(fmaf(2.f, go.x, -sv.x), fmaf(2.f, go.y, -sv.y),
                                 fmaf(2.f, go.z, -sv.z), fmaf(2.f, go.w, -sv.w));
        bC[n] = t2o; stb(basis, sb, 3, row, rchp, t2o);
        float4 t2i = make_float4(fmaf(fiv2, gi.x, -sv.x), fmaf(fiv2, gi.y, -sv.y),
                                 fmaf(fiv2, gi.z, -sv.z), fmaf(fiv2, gi.w, -sv.w));
        bX[n] = t2i; stb(basis, sb, 4, row, rchp, t2i);
    }
    __syncthreads();
    // ph56: T3o = 2*gO(bC)-T1o -> bB (j5); T3i = fiv2*gI(bX)-T1o -> bA (j6)
    if (act) {
        float4 go = gO4(bC, eo, e0o, e1o);
        float4 gi = gI4(bX, eid, e0i, e1i);
        float4 sv = bA[n];
        float4 t3o = make_float4(fmaf(2.f, go.x, -sv.x), fmaf(2.f, go.y, -sv.y),
                                 fmaf(2.f, go.z, -sv.z), fmaf(2.f, go.w, -sv.w));
        bB[n] = t3o; stb(basis, sb, 5, row, rchp, t3o);
        float4 t3i = make_float4(fmaf(fiv2, gi.x, -sv.x), fmaf(fiv2, gi.y, -sv.y),
                                 fmaf(fiv2, gi.z, -sv.z), fmaf(fiv2, gi.w, -sv.w));
        bA[n] = t3i; stb(basis, sb, 6, row, rchp, t3i);
    }
    __syncthreads();
    // ph78: T4o = 2*gO(bB)-T2o (j7); T4i = fiv2*gI(bA)-T2o (j8); no LDS writes
    if (act) {
        float4 go = gO4(bB, eo, e0o, e1o);
        float4 gi = gI4(bA, eid, e0i, e1i);
        float4 sv = bC[n];
        float4 t4o = make_float4(fmaf(2.f, go.x, -sv.x), fmaf(2.f, go.y, -sv.y),
                                 fmaf(2.f, go.z, -sv.z), fmaf(2.f, go.w, -sv.w));
        stb(basis, sb, 7, row, rchp, t4o);
        float4 t4i = make_float4(fmaf(fiv2, gi.x, -sv.x), fmaf(fiv2, gi.y, -sv.y),
                                 fmaf(fiv2, gi.z, -sv.z), fmaf(fiv2, gi.w, -sv.w));
        stb(basis, sb, 8, row, rchp, t4i);
    }
}

// ---------------- phase 2: GEMM [rchp,576]@[576,128] + gates + LN -> hnc (chunk-local) ----------------

__global__ __launch_bounds__(256, 4) void k_gemm(const u16* __restrict__ basis,
        const u16* __restrict__ wt, const void* __restrict__ bz, const void* __restrict__ bh,
        const void* __restrict__ lng, const void* __restrict__ lnb, u16* __restrict__ hnc,
        int rchp, int rchv, const int* __restrict__ flags) {
    union SM {
        struct { u16 A[8 * 128 * 4]; u16 B[128 * 40]; } st;
        float heh[128 * 65];
    };
    __shared__ SM sm;
    __shared__ float sMu[128], sRs[128];
    __shared__ float sBz[64], sBh[64], sG[64], sB2[64];

    const int tid = threadIdx.x;
    if (tid < 64) {
        const int f32m = flags[0];
        sBz[tid] = ldf(bz, tid, f32m); sBh[tid] = ldf(bh, tid, f32m);
        sG[tid] = ldf(lng, tid, f32m); sB2[tid] = ldf(lnb, tid, f32m);
    }
    const int lane = tid & 63, wv = tid >> 6;
    const int wr = wv >> 1, wc = wv & 1;
    const int m = lane & 15, q = lane >> 4;
    const int r0 = blockIdx.x * 128;

    f32x4_t acc[4][4];
    const f32x4_t zero = {0.f, 0.f, 0.f, 0.f};
    for (int mi = 0; mi < 4; ++mi)
        for (int ni = 0; ni < 4; ++ni) acc[mi][ni] = zero;

    for (int t = 0; t < 18; ++t) {
        const int j = t >> 1, hf = t & 1;
        #pragma unroll
        for (int p = 0; p < 2; ++p) {
            int lin = p * 256 + tid;
            int sbp = lin >> 6, rp = lin & 63;
            const u16* src = basis + ((size_t)((hf * 8 + sbp) * 9 + j) * rchp + r0 + rp * 2) * 4;
            *(uint4*)(&sm.st.A[lin * 8]) = *(const uint4*)src;
        }
        #pragma unroll
        for (int p = 0; p < 2; ++p) {
            int lin = p * 256 + tid;
            int c = lin >> 2, qq = lin & 3;
            const u16* src = wt + c * 576 + t * 32 + qq * 8;
            *(uint4*)(&sm.st.B[c * 40 + qq * 8]) = *(const uint4*)src;
        }
        __syncthreads();
        s16x8_t af[4], bfr[4];
        #pragma unroll
        for (int mi = 0; mi < 4; ++mi) {
            int r = wr * 64 + mi * 16 + m;
            s16x4_t lo = *(const s16x4_t*)&sm.st.A[(2 * q) * 512 + r * 4];
            s16x4_t hi = *(const s16x4_t*)&sm.st.A[(2 * q + 1) * 512 + r * 4];
            af[mi] = __builtin_shufflevector(lo, hi, 0, 1, 2, 3, 4, 5, 6, 7);
        }
        #pragma unroll
        for (int ni = 0; ni < 4; ++ni) {
            int c = (ni < 2) ? (wc * 32 + ni * 16 + m) : (64 + wc * 32 + (ni - 2) * 16 + m);
            bfr[ni] = *(const s16x8_t*)&sm.st.B[c * 40 + q * 8];
        }
        #pragma unroll
        for (int mi = 0; mi < 4; ++mi)
            #pragma unroll
            for (int ni = 0; ni < 4; ++ni)
                acc[mi][ni] = __builtin_amdgcn_mfma_f32_16x16x32_bf16(af[mi], bfr[ni], acc[mi][ni], 0, 0, 0);
        __syncthreads();
    }

    #pragma unroll
    for (int mi = 0; mi < 4; ++mi) {
        #pragma unroll
        for (int ni = 0; ni < 2; ++ni) {
            const int f = wc * 32 + ni * 16 + m;
            const float vbz = sBz[f], vbh = sBh[f];
            #pragma unroll
            for (int r = 0; r < 4; ++r) {
                const int rl = wr * 64 + mi * 16 + q * 4 + r;
                float zp = acc[mi][ni][r];
                float hp = acc[mi][ni + 2][r];
                zp = (zp == zp) ? zp : 0.f;
                hp = (hp == hp) ? hp : 0.f;
                zp = fminf(fmaxf(zp + vbz, -30.f), 30.f);
                hp = fminf(fmaxf(hp + vbh, -15.f), 15.f);
                const float z = __fdividef(1.f, 1.f + __expf(-zp));
                const float e2 = __expf(2.f * hp);
                const float ht = __fdividef(e2 - 1.f, e2 + 1.f);
                float h = (1.f - z) * ht;
                h = fmaxf(h, 0.f);
                sm.heh[rl * 65 + f] = h;
            }
        }
    }
    __syncthreads();
    if (tid < 128) {
        float sum = 0.f, ss = 0.f;
        #pragma unroll 8
        for (int f = 0; f < 64; ++f) {
            float v = sm.heh[tid * 65 + f];
            sum += v; ss += v * v;
        }
        float mu = sum * 0.015625f;
        float var = fmaxf(ss * 0.015625f - mu * mu, 0.f);
        sMu[tid] = mu;
        sRs[tid] = rsqrtf(var + 1e-5f);
    }
    __syncthreads();
    for (int idx = tid; idx < 128 * 64; idx += 256) {
        int rl = idx >> 6, f = idx & 63;
        if (r0 + rl < rchv) {
            float v = (sm.heh[rl * 65 + f] - sMu[rl]) * sRs[rl] * sG[f] + sB2[f];
            hnc[(size_t)(r0 + rl) * 64 + f] = f2bf(v);
        }
    }
}

// ---------------- phase 3: chunked final linear (accumulates into partials) ----------------

__global__ __launch_bounds__(256) void k_lin_chunk(const u16* __restrict__ hnc,
        const void* __restrict__ lw, float* __restrict__ partials, int s0, int chs,
        const int* __restrict__ flags) {
    const int tid = threadIdx.x;
    const int f32m = flags[0];
    float acc[NB][NC];
    #pragma unroll
    for (int b = 0; b < NB; ++b)
        #pragma unroll
        for (int c = 0; c < NC; ++c) acc[b][c] = 0.f;

    const int hi_s = s0 + chs - 1;
    for (int w = blockIdx.x * 256 + tid; w < TNF; w += LWG * 256) {
        const int t = w / 64000;
        int blo_n = s0 - t + 11;
        const int blo = (blo_n > 0) ? (blo_n / 12) : 0;
        const int bhi_n = hi_s - t;
        const int bhi = (bhi_n >= 0) ? (bhi_n / 12) : -1;
        if (bhi < blo) continue;
        float wvv[NC];
        if (f32m) {
            #pragma unroll
            for (int c = 0; c < NC; ++c) wvv[c] = ((const float*)lw)[(size_t)c * TNF + w];
        } else {
            #pragma unroll
            for (int c = 0; c < NC; ++c) wvv[c] = bf2f(((const u16*)lw)[(size_t)c * TNF + w]);
        }
        #pragma unroll
        for (int c = 0; c < NC; ++c) {
            float v = wvv[c];
            wvv[c] = (v == v && v > -1e30f && v < 1e30f) ? v : 0.f;
        }
        #pragma unroll
        for (int b = 0; b < NB; ++b) {
            if (b >= blo && b <= bhi) {
                const int sl = b * 12 + t - s0;
                const float h = bf2f(hnc[(size_t)sl * 64000 + (w - t * 64000)]);
                #pragma unroll
                for (int c = 0; c < NC; ++c) acc[b][c] = fmaf(h, wvv[c], acc[b][c]);
            }
        }
    }
    __shared__ float sRed[4][160];
    const int wvi = tid >> 6, lane = tid & 63;
    #pragma unroll
    for (int b = 0; b < NB; ++b)
        #pragma unroll
        for (int c = 0; c < NC; ++c) {
            float v = acc[b][c];
            #pragma unroll
            for (int off = 1; off < 64; off <<= 1) v += __shfl_xor(v, off, 64);
            if (lane == 0) sRed[wvi][b * NC + c] = v;
        }
    __syncthreads();
    if (tid < 160)
        partials[(size_t)blockIdx.x * 160 + tid] +=
            sRed[0][tid] + sRed[1][tid] + sRed[2][tid] + sRed[3][tid];
}

__global__ void k_red(const float* __restrict__ partials, const void* __restrict__ lb,
                      void* __restrict__ out, const int* __restrict__ flags) {
    const int o = threadIdx.x;
    const int f32m = flags[0];
    if (o < 160) {
        float s = ldf(lb, o % NC, f32m);
        #pragma unroll 8
        for (int wg = 0; wg < LWG; ++wg) s += partials[(size_t)wg * 160 + o];
        if (f32m) ((float*)out)[o] = s;
        else      ((u16*)out)[o] = f2bf(s);
    }
}

// ---------------- launch ----------------

extern "C" void kernel_launch(void* const* d_in, const int* in_sizes, int n_in,
                              void* d_out, int out_size, void* d_ws, size_t ws_size,
                              hipStream_t stream) {
    (void)in_sizes; (void)n_in; (void)out_size;
    const void* x   = d_in[0];
    const int*  ei  = (const int*)d_in[1];
    const void* Wz  = d_in[2];
    const void* bz  = d_in[3];
    const void* Wh  = d_in[6];
    const void* bh  = d_in[7];
    const void* lng = d_in[8];
    const void* lnb = d_in[9];
    const void* lw  = d_in[10];
    const void* lb  = d_in[11];

    char* ws = (char*)d_ws;
    size_t off = 0;
    auto alloc = [&](size_t bytes) -> void* {
        void* p = ws + off;
        off = (off + bytes + 255) & ~(size_t)255;
        return p;
    };
    int*   flags    = (int*)  alloc(64);
    u16*   wt       = (u16*)  alloc(128 * 576 * 2);
    int*   ints     = (int*)  alloc(4000 * 4);
    int*   ooff     = (int*)  alloc(1024 * 4);
    int*   ioff     = (int*)  alloc(1024 * 4);
    float* inv_o    = (float*)alloc(1000 * 4);
    float* inv_i    = (float*)alloc(1000 * 4);
    int2*  eo       = (int2*) alloc((size_t)EE * 8);
    int*   eid      = (int*)  alloc((size_t)EE * 4);
    float* partials = (float*)alloc((size_t)LWG * 160 * 4);

    const int cand[] = {192, 96, 64, 48, 32, 24, 16, 12, 8, 6, 4, 3, 2, 1};
    int CHS = 1, RCHP = 1024;
    for (int ci = 0; ci < 14; ++ci) {
        int c = cand[ci];
        int rchp = ((c * NN + 127) / 128) * 128;
        size_t need = (size_t)16 * 9 * rchp * 8 + (size_t)c * NN * FF * 2 + 8192;
        if (off + need <= ws_size) { CHS = c; RCHP = rchp; break; }
    }
    u16* basis = (u16*)alloc((size_t)16 * 9 * RCHP * 8);
    u16* hnc   = (u16*)alloc((size_t)CHS * NN * FF * 2);

    int* deg_out = ints;
    int* deg_in  = ints + 1000;
    int* cur     = ints + 2000;

    k_detect<<<1, 64, 0, stream>>>((const u16*)x, ei, flags);
    k_zero<<<16, 256, 0, stream>>>(ints);
    k_zpart<<<(LWG * 160 + 255) / 256, 256, 0, stream>>>(partials);
    k_deg<<<(EE + 255) / 256, 256, 0, stream>>>(ei, ints, flags);
    k_scan<<<1, 1024, 0, stream>>>(deg_in, deg_out, ooff, ioff, inv_o, inv_i);
    k_fill<<<(EE + 255) / 256, 256, 0, stream>>>(ei, ooff, ioff, inv_o, cur, eo, eid, flags);
    k_wt<<<288, 256, 0, stream>>>(Wz, Wh, wt, flags);
    const int nchunk = SS / CHS;
    for (int ch = 0; ch < nchunk; ++ch) {
        k_cheb<<<CHS * 16, 1024, 0, stream>>>(x, eo, ooff, eid, ioff, inv_i, basis,
                                              ch * CHS, RCHP, flags, CHS);
        k_gemm<<<RCHP / 128, 256, 0, stream>>>(basis, wt, bz, bh, lng, lnb, hnc,
                                               RCHP, CHS * NN, flags);
        k_lin_chunk<<<LWG, 256, 0, stream>>>(hnc, lw, partials, ch * CHS, CHS, flags);
    }
    k_red<<<1, 256, 0, stream>>>(partials, lb, d_out, flags);
}